// Round 17
// baseline (1020.313 us; speedup 1.0000x reference)
//
#include <hip/hip_runtime.h>
#include <math.h>

#define NN 16384
#define KK 16
#define RPW 4                       // rows per scan wave
#define SW 4                        // scan waves per block
#define FW 4                        // fill waves per block
#define RPB (SW * RPW)              // 16 rows per block (ORIGINAL order, contiguous)
#define CAP 128                     // per-row candidate buffer (u64 keys)
#define NB 1024                     // x-sort buckets
#define NT 64                       // tiles of 256 sorted points

typedef float f32x4 __attribute__((ext_vector_type(4)));
typedef unsigned long long u64;

// ---- d_ws layout (bytes): pts | perm | hist | cur | tileMM  (~338 KB) ----
#define WS_PTS   0
#define WS_PERM  (NN * 16)
#define WS_HIST  (WS_PERM + NN * 4)
#define WS_CUR   (WS_HIST + NB * 4)
#define WS_TMM   (WS_CUR + NB * 4)

// ---------------- sort pipeline (5 tiny kernels, r15/r16-verified) ----------
__global__ void zero_hist(int* __restrict__ hist) { hist[threadIdx.x] = 0; }

__device__ __forceinline__ int xbucket(float x) {
    int b = (int)((x + 6.0f) * (NB / 12.0f));
    return b < 0 ? 0 : (b > NB - 1 ? NB - 1 : b);
}

__global__ void hist_kernel(const float* __restrict__ nodes, int* __restrict__ hist) {
    const int i = blockIdx.x * 256 + threadIdx.x;
    atomicAdd(&hist[xbucket(nodes[3 * i])], 1);
}

__global__ void scan_kernel(const int* __restrict__ hist, int* __restrict__ cur) {
    __shared__ int s[NB];
    const int tid = threadIdx.x;
    const int h0 = hist[tid];
    s[tid] = h0; __syncthreads();
    for (int o = 1; o < NB; o <<= 1) {
        const int v = (tid >= o) ? s[tid - o] : 0;
        __syncthreads();
        s[tid] += v;
        __syncthreads();
    }
    cur[tid] = s[tid] - h0;     // exclusive prefix
}

__global__ void scatter_kernel(const float* __restrict__ nodes, int* __restrict__ cur,
                               float4* __restrict__ pts, int* __restrict__ perm) {
#pragma clang fp contract(off)
    const int i = blockIdx.x * 256 + threadIdx.x;
    const float x = nodes[3 * i], y = nodes[3 * i + 1], z = nodes[3 * i + 2];
    const float sq = (x * x + y * y) + z * z;     // reference arithmetic
    const int pos = atomicAdd(&cur[xbucket(x)], 1);
    pts[pos] = make_float4(x, y, z, sq);
    perm[pos] = i;
}
// after scatter, cur[b] = inclusive end position of bucket b (used for tile lookup)

__global__ void bounds_kernel(const float4* __restrict__ pts, float2* __restrict__ tmm) {
    __shared__ float mn[256], mx[256];
    const int tid = threadIdx.x;
    const float x = pts[blockIdx.x * 256 + tid].x;
    mn[tid] = x; mx[tid] = x; __syncthreads();
    for (int o = 128; o >= 1; o >>= 1) {
        if (tid < o) { mn[tid] = fminf(mn[tid], mn[tid + o]); mx[tid] = fmaxf(mx[tid], mx[tid + o]); }
        __syncthreads();
    }
    if (tid == 0) tmm[blockIdx.x] = make_float2(mn[0], mx[0]);
}

// ---------------- verified helpers ----------------
__device__ __forceinline__ float bcastf(float v, int l) {
    return __int_as_float(__builtin_amdgcn_readlane(__float_as_int(v), l));
}
__device__ __forceinline__ bool lexless(float da, int ia, float db, int ib) {
    return (da < db) || ((da == db) && (ia < ib));
}
// r1-r6-verified distributed insert — overflow fallback only.
__device__ __forceinline__ void insert_tile(bool rough, float d2, int j,
                                            float& ld, int& li,
                                            float& td, int& ti, float& td2u,
                                            int lane) {
#pragma clang fp contract(off)
    if (!__any(rough)) return;
    float dist = INFINITY;
    if (rough) dist = sqrtf(fmaxf(d2, 0.0f));
    bool done = false;
    while (true) {
        const bool pass = (!done) && rough && lexless(dist, j, td, ti);
        const u64 m = __ballot(pass);
        if (m == 0ull) break;
        const int src = __ffsll(m) - 1;
        const float dc = __shfl(dist, src);
        const int   ic = __shfl(j, src);
        if (lane == src) done = true;
        const bool gt = lexless(dc, ic, ld, li);
        const u64 gm = __ballot(gt);
        const int p = __ffsll(gm) - 1;
        const float pd = __shfl_up(ld, 1);
        const int   pi = __shfl_up(li, 1);
        if (gt) {
            if (lane == p) { ld = dc; li = ic; }
            else           { ld = pd; li = pi; }
        }
        td = __shfl(ld, 16);
        ti = __shfl(li, 16);
        td2u = td * td * 1.000001f;
    }
}

// -------- main kernel: 4 scan waves + 4 fill waves, 16 contiguous rows ------
__global__ __launch_bounds__(512) void knn_main(const float4* __restrict__ pts,
                                                const int* __restrict__ perm,
                                                const int* __restrict__ cur,
                                                const float2* __restrict__ tmm_g,
                                                const float* __restrict__ nodes,
                                                float* __restrict__ out) {
#pragma clang fp contract(off)
    const int lane = threadIdx.x & 63;
    const int wid  = threadIdx.x >> 6;
    const int tid  = threadIdx.x;
    const int rowBase = blockIdx.x * RPB;   // ORIGINAL row index, contiguous

    __shared__ float2 tmm[NT];
    __shared__ u64 buf[SW][RPW][CAP];
    __shared__ int cnt[SW][RPW];
    __shared__ int nb[RPB][KK];             // original col indices

    if (tid < NT) tmm[tid] = tmm_g[tid];
    __syncthreads();

    if (wid >= SW) {
        // ---- fill waves: zero 4 contiguous rows (256 KB) each ----
        // PLAIN cached stores (NOT nontemporal): nt stores bypass L2
        // allocation and force a ~1 GB line-fetch/RMW stream (r16 FETCH_SIZE
        // = 1.5 GB). Plain stores merge into full dirty L2 lines -> zero
        // fetch, rocclr-fill behavior (FETCH ~40 KB at 6.6 TB/s).
        const int fr = (wid - SW) * 4;      // local row base
        f32x4* ob = (f32x4*)(out + (size_t)(rowBase + fr) * NN);
        const f32x4 z4 = {0.f, 0.f, 0.f, 0.f};
#pragma unroll 8
        for (int k = 0; k < 4 * (NN / 4) / 64; ++k)
            ob[k * 64 + lane] = z4;
        // Drain so this wave's later 1.0 stores are ordered after the zeros.
        asm volatile("s_waitcnt vmcnt(0)" ::: "memory");
    } else {
        // ---- scan waves: 4 rows each ----
        float xs[RPW], ys[RPW], zs[RPW], ss[RPW];
        int tc[RPW];
#pragma unroll
        for (int r = 0; r < RPW; ++r) {
            const int row = rowBase + wid * RPW + r;
            xs[r] = nodes[3 * row];
            ys[r] = nodes[3 * row + 1];
            zs[r] = nodes[3 * row + 2];
            ss[r] = (xs[r] * xs[r] + ys[r] * ys[r]) + zs[r] * zs[r];  // ref arith
            // Row's sorted tile via bucket end position (row lies within
            // [cur[b]-hist[b], cur[b]) -> its tile is t or t-1; t-1..t+1 covers).
            int t = (cur[xbucket(xs[r])] - 1) >> 8;
            t = t - 1; t = t < 0 ? 0 : (t > NT - 3 ? NT - 3 : t);
            tc[r] = t;
        }

        // ===== tau phase: 3 local tiles per row (768 actual candidates) =====
        float rm[RPW];
#pragma unroll
        for (int r = 0; r < RPW; ++r) rm[r] = INFINITY;
#pragma unroll
        for (int r = 0; r < RPW; ++r) {
            for (int tt = 0; tt < 3; ++tt) {
                const int tb = (tc[r] + tt) * 256;
                const float4 q0 = pts[tb + lane];
                const float4 q1 = pts[tb + 64 + lane];
                const float4 q2 = pts[tb + 128 + lane];
                const float4 q3 = pts[tb + 192 + lane];
                const float d0 = (ss[r] + q0.w) - 2.0f * fmaf(zs[r], q0.z, fmaf(ys[r], q0.y, xs[r] * q0.x));
                const float d1 = (ss[r] + q1.w) - 2.0f * fmaf(zs[r], q1.z, fmaf(ys[r], q1.y, xs[r] * q1.x));
                const float d2 = (ss[r] + q2.w) - 2.0f * fmaf(zs[r], q2.z, fmaf(ys[r], q2.y, xs[r] * q2.x));
                const float d3 = (ss[r] + q3.w) - 2.0f * fmaf(zs[r], q3.z, fmaf(ys[r], q3.y, xs[r] * q3.x));
                rm[r] = fminf(rm[r], fminf(fminf(d0, d1), fminf(d2, d3)));
            }
        }
        // r12-verified bitonic sort of 64 lane-mins; tau = 17th (conservative:
        // 17 distinct sampled candidates have d2 <= tau -> C >= 17).
        float sv[RPW];
#pragma unroll
        for (int r = 0; r < RPW; ++r) sv[r] = rm[r];
#pragma unroll
        for (int k = 2; k <= 64; k <<= 1) {
#pragma unroll
            for (int j = k >> 1; j >= 1; j >>= 1) {
                const bool keepmin = (((lane & j) == 0) == ((lane & k) == 0));
#pragma unroll
                for (int r = 0; r < RPW; ++r) {
                    const float o = __shfl_xor(sv[r], j);
                    sv[r] = keepmin ? fminf(sv[r], o) : fmaxf(sv[r], o);
                }
            }
        }
        float tau[RPW];
#pragma unroll
        for (int r = 0; r < RPW; ++r)   // *1.000002+eps: sqrt-tie-collapse guard
            tau[r] = fmaxf(bcastf(sv[r], 16), 0.0f) * 1.000002f + 1e-30f;

        if (lane < RPW) cnt[wid][lane] = 0;
        asm volatile("s_waitcnt lgkmcnt(0)" ::: "memory");

        // ===== screen pass: AABB-pruned tiles, r15/r16-verified body =====
        for (int t = 0; t < NT; ++t) {
            const float2 mm = tmm[t];
            bool kp[RPW]; bool anyk = false;
#pragma unroll
            for (int r = 0; r < RPW; ++r) {
                const float dx = fmaxf(fmaxf(mm.x - xs[r], xs[r] - mm.y), 0.0f);
                // prune slack: fp32 cancellation bound on ref-d2 vs true-d2
                kp[r] = (dx * dx <= tau[r] * 1.00001f + 5e-5f);
                anyk |= kp[r];
            }
            if (!anyk) continue;        // wave-uniform skip
            const int base = t * 256;
            const float4 q0 = pts[base + lane];
            const float4 q1 = pts[base + 64 + lane];
            const float4 q2 = pts[base + 128 + lane];
            const float4 q3 = pts[base + 192 + lane];
#pragma unroll
            for (int r = 0; r < RPW; ++r) {
                if (!kp[r]) continue;
                const float d0 = (ss[r] + q0.w) - 2.0f * fmaf(zs[r], q0.z, fmaf(ys[r], q0.y, xs[r] * q0.x));
                const float d1 = (ss[r] + q1.w) - 2.0f * fmaf(zs[r], q1.z, fmaf(ys[r], q1.y, xs[r] * q1.x));
                const float d2 = (ss[r] + q2.w) - 2.0f * fmaf(zs[r], q2.z, fmaf(ys[r], q2.y, xs[r] * q2.x));
                const float d3 = (ss[r] + q3.w) - 2.0f * fmaf(zs[r], q3.z, fmaf(ys[r], q3.y, xs[r] * q3.x));
                const bool p0 = d0 <= tau[r], p1 = d1 <= tau[r];
                const bool p2 = d2 <= tau[r], p3 = d3 <= tau[r];
                if (p0 | p1 | p2 | p3) {
                    if (p0) { const int o = atomicAdd(&cnt[wid][r], 1);
                              if (o < CAP) buf[wid][r][o] = (((u64)__float_as_uint(fmaxf(d0, 0.f))) << 32) | (unsigned)(base + lane); }
                    if (p1) { const int o = atomicAdd(&cnt[wid][r], 1);
                              if (o < CAP) buf[wid][r][o] = (((u64)__float_as_uint(fmaxf(d1, 0.f))) << 32) | (unsigned)(base + 64 + lane); }
                    if (p2) { const int o = atomicAdd(&cnt[wid][r], 1);
                              if (o < CAP) buf[wid][r][o] = (((u64)__float_as_uint(fmaxf(d2, 0.f))) << 32) | (unsigned)(base + 128 + lane); }
                    if (p3) { const int o = atomicAdd(&cnt[wid][r], 1);
                              if (o < CAP) buf[wid][r][o] = (((u64)__float_as_uint(fmaxf(d3, 0.f))) << 32) | (unsigned)(base + 192 + lane); }
                }
            }
        }
        asm volatile("s_waitcnt lgkmcnt(0)" ::: "memory");

        // ===== select: exact lex-(dist, ORIGINAL idx) rank (r14/r15-verified) =====
#pragma unroll
        for (int r = 0; r < RPW; ++r) {
            const int C = cnt[wid][r];
            const int rowl = wid * RPW + r;
            if (C <= CAP) {                 // C >= 17 guaranteed (tau subset bound)
                for (int e = lane; e < C; e += 64) {
                    const u64 k2 = buf[wid][r][e];
                    const float dd = sqrtf(__uint_as_float((unsigned)(k2 >> 32)));
                    const int oi = perm[(int)(k2 & 0xffffffffu)];   // sorted -> orig
                    buf[wid][r][e] = (((u64)__float_as_uint(dd)) << 32) | (unsigned)oi;
                }
                asm volatile("s_waitcnt lgkmcnt(0) vmcnt(0)" ::: "memory");
                for (int e = lane; e < C; e += 64) {
                    const u64 my = buf[wid][r][e];
                    int rk = 0;
                    for (int c = 0; c < C; ++c)
                        rk += (buf[wid][r][c] < my) ? 1 : 0;   // orig idx unique
                    if (rk >= 1 && rk <= KK)
                        nb[rowl][rk - 1] = (int)(my & 0xffffffffu);  // rank 0 dropped
                }
            } else {
                // Pathological overflow: verified full-scan insert, orig-idx keys.
                float ld = INFINITY; int li = 0x7fffffff;
                float td = INFINITY; int ti = 0x7fffffff; float t2 = INFINITY;
                for (int tt = 0; tt < NN / 64; ++tt) {
                    const int j = tt * 64 + lane;
                    const float4 q = pts[j];
                    const int oi = perm[j];
                    const float dd = (ss[r] + q.w) - 2.0f * fmaf(zs[r], q.z, fmaf(ys[r], q.y, xs[r] * q.x));
                    insert_tile(dd <= t2, dd, oi, ld, li, td, ti, t2, lane);
                }
                if (lane >= 1 && lane <= KK) nb[rowl][lane - 1] = li;
            }
        }
    }

    __syncthreads();

    // Fill waves write the ones for THEIR OWN rows (same-wave ordering after
    // the vmcnt(0) drain of their zeros — r6/r14-verified pattern; with
    // cached stores the L2 line merge preserves the same-address order).
    if (wid >= SW) {
        const int rl = (wid - SW) * 4 + (lane >> 4);   // 4 rows x 16 cols = 64 lanes
        out[(size_t)(rowBase + rl) * NN + nb[rl][lane & 15]] = 1.0f;
    }
}

extern "C" void kernel_launch(void* const* d_in, const int* in_sizes, int n_in,
                              void* d_out, int out_size, void* d_ws, size_t ws_size,
                              hipStream_t stream) {
    const float* nodes = (const float*)d_in[0];
    float* out = (float*)d_out;
    (void)in_sizes; (void)n_in; (void)out_size; (void)ws_size;

    char* ws = (char*)d_ws;
    float4* pts  = (float4*)(ws + WS_PTS);
    int*    perm = (int*)   (ws + WS_PERM);
    int*    hist = (int*)   (ws + WS_HIST);
    int*    cur  = (int*)   (ws + WS_CUR);
    float2* tmm  = (float2*)(ws + WS_TMM);

    hipLaunchKernelGGL(zero_hist,     dim3(1),        dim3(NB),  0, stream, hist);
    hipLaunchKernelGGL(hist_kernel,   dim3(NN / 256), dim3(256), 0, stream, nodes, hist);
    hipLaunchKernelGGL(scan_kernel,   dim3(1),        dim3(NB),  0, stream, hist, cur);
    hipLaunchKernelGGL(scatter_kernel,dim3(NN / 256), dim3(256), 0, stream, nodes, cur, pts, perm);
    hipLaunchKernelGGL(bounds_kernel, dim3(NT),       dim3(256), 0, stream, pts, tmm);
    hipLaunchKernelGGL(knn_main,      dim3(NN / RPB), dim3(512), 0, stream,
                       pts, perm, cur, tmm, nodes, out);
}

// Round 18
// 810.234 us; speedup vs baseline: 1.2593x; 1.2593x over previous
//
#include <hip/hip_runtime.h>
#include <math.h>

#define NN 16384
#define KK 16
#define RPW 4                       // rows per scan wave
#define SW 4                        // scan waves per block
#define RPB (SW * RPW)              // 16 rows per block
#define CAP 128                     // per-row candidate buffer (u64 keys)
#define NB 1024                     // x-sort buckets
#define NT 64                       // tiles of 256 sorted points
#define FILL_BLOCKS 2048

typedef float f32x4 __attribute__((ext_vector_type(4)));
typedef unsigned long long u64;

// ---- d_ws layout (bytes): pts | perm | hist | cur | tileMM  (~338 KB) ----
#define WS_PTS   0
#define WS_PERM  (NN * 16)
#define WS_HIST  (WS_PERM + NN * 4)
#define WS_CUR   (WS_HIST + NB * 4)
#define WS_TMM   (WS_CUR + NB * 4)

// ---------------- sort pipeline (5 tiny kernels, r15-r17-verified) ----------
__global__ void zero_hist(int* __restrict__ hist) { hist[threadIdx.x] = 0; }

__device__ __forceinline__ int xbucket(float x) {
    int b = (int)((x + 6.0f) * (NB / 12.0f));
    return b < 0 ? 0 : (b > NB - 1 ? NB - 1 : b);
}

__global__ void hist_kernel(const float* __restrict__ nodes, int* __restrict__ hist) {
    const int i = blockIdx.x * 256 + threadIdx.x;
    atomicAdd(&hist[xbucket(nodes[3 * i])], 1);
}

__global__ void scan_kernel(const int* __restrict__ hist, int* __restrict__ cur) {
    __shared__ int s[NB];
    const int tid = threadIdx.x;
    const int h0 = hist[tid];
    s[tid] = h0; __syncthreads();
    for (int o = 1; o < NB; o <<= 1) {
        const int v = (tid >= o) ? s[tid - o] : 0;
        __syncthreads();
        s[tid] += v;
        __syncthreads();
    }
    cur[tid] = s[tid] - h0;     // exclusive prefix
}

__global__ void scatter_kernel(const float* __restrict__ nodes, int* __restrict__ cur,
                               float4* __restrict__ pts, int* __restrict__ perm) {
#pragma clang fp contract(off)
    const int i = blockIdx.x * 256 + threadIdx.x;
    const float x = nodes[3 * i], y = nodes[3 * i + 1], z = nodes[3 * i + 2];
    const float sq = (x * x + y * y) + z * z;     // reference arithmetic
    const int pos = atomicAdd(&cur[xbucket(x)], 1);
    pts[pos] = make_float4(x, y, z, sq);
    perm[pos] = i;
}
// after scatter, cur[b] = inclusive end position of bucket b (tile lookup)

__global__ void bounds_kernel(const float4* __restrict__ pts, float2* __restrict__ tmm) {
    __shared__ float mn[256], mx[256];
    const int tid = threadIdx.x;
    const float x = pts[blockIdx.x * 256 + tid].x;
    mn[tid] = x; mx[tid] = x; __syncthreads();
    for (int o = 128; o >= 1; o >>= 1) {
        if (tid < o) { mn[tid] = fminf(mn[tid], mn[tid + o]); mx[tid] = fmaxf(mx[tid], mx[tid + o]); }
        __syncthreads();
    }
    if (tid == 0) tmm[blockIdx.x] = make_float2(mn[0], mx[0]);
}

// ---------------- dedicated fill: rocclr-fill shape, plain cached stores ----
// (r17 measured: plain stores -> FETCH ~6.5 MB, no RMW stream. Dedicated
// kernel shape measured ~175 us in r5.)
__global__ __launch_bounds__(256) void fill_zero(f32x4* __restrict__ ob) {
    const int tid = blockIdx.x * 256 + threadIdx.x;
    const int nthreads = FILL_BLOCKS * 256;
    const f32x4 z4 = {0.f, 0.f, 0.f, 0.f};
#pragma unroll 4
    for (int k = 0; k < (NN * (NN / 4)) / nthreads; ++k)   // 128 iterations
        ob[(size_t)k * nthreads + tid] = z4;
}

// ---------------- verified helpers ----------------
__device__ __forceinline__ float bcastf(float v, int l) {
    return __int_as_float(__builtin_amdgcn_readlane(__float_as_int(v), l));
}
__device__ __forceinline__ bool lexless(float da, int ia, float db, int ib) {
    return (da < db) || ((da == db) && (ia < ib));
}
// r1-r6-verified distributed insert — overflow fallback only.
__device__ __forceinline__ void insert_tile(bool rough, float d2, int j,
                                            float& ld, int& li,
                                            float& td, int& ti, float& td2u,
                                            int lane) {
#pragma clang fp contract(off)
    if (!__any(rough)) return;
    float dist = INFINITY;
    if (rough) dist = sqrtf(fmaxf(d2, 0.0f));
    bool done = false;
    while (true) {
        const bool pass = (!done) && rough && lexless(dist, j, td, ti);
        const u64 m = __ballot(pass);
        if (m == 0ull) break;
        const int src = __ffsll(m) - 1;
        const float dc = __shfl(dist, src);
        const int   ic = __shfl(j, src);
        if (lane == src) done = true;
        const bool gt = lexless(dc, ic, ld, li);
        const u64 gm = __ballot(gt);
        const int p = __ffsll(gm) - 1;
        const float pd = __shfl_up(ld, 1);
        const int   pi = __shfl_up(li, 1);
        if (gt) {
            if (lane == p) { ld = dc; li = ic; }
            else           { ld = pd; li = pi; }
        }
        td = __shfl(ld, 16);
        ti = __shfl(li, 16);
        td2u = td * td * 1.000001f;
    }
}

// ---------- dedicated scan: 4 scan waves x 4 rows; ones written directly ----
// Runs AFTER fill_zero on the stream -> no intra-kernel ordering tricks needed.
__global__ __launch_bounds__(256) void knn_scan(const float4* __restrict__ pts,
                                                const int* __restrict__ perm,
                                                const int* __restrict__ cur,
                                                const float2* __restrict__ tmm_g,
                                                const float* __restrict__ nodes,
                                                float* __restrict__ out) {
#pragma clang fp contract(off)
    const int lane = threadIdx.x & 63;
    const int wid  = threadIdx.x >> 6;
    const int tid  = threadIdx.x;
    const int rowBase = blockIdx.x * RPB;   // ORIGINAL row index, contiguous

    __shared__ float2 tmm[NT];
    __shared__ u64 buf[SW][RPW][CAP];
    __shared__ int cnt[SW][RPW];

    if (tid < NT) tmm[tid] = tmm_g[tid];
    __syncthreads();

    // ---- per-row setup (reference arithmetic) + home-tile lookup ----
    float xs[RPW], ys[RPW], zs[RPW], ss[RPW];
    int tc[RPW];
#pragma unroll
    for (int r = 0; r < RPW; ++r) {
        const int row = rowBase + wid * RPW + r;
        xs[r] = nodes[3 * row];
        ys[r] = nodes[3 * row + 1];
        zs[r] = nodes[3 * row + 2];
        ss[r] = (xs[r] * xs[r] + ys[r] * ys[r]) + zs[r] * zs[r];
        int t = (cur[xbucket(xs[r])] - 1) >> 8;
        t = t - 1; t = t < 0 ? 0 : (t > NT - 3 ? NT - 3 : t);
        tc[r] = t;
    }

    // ===== tau phase: 3 local tiles per row (768 actual candidates) =====
    float rm[RPW];
#pragma unroll
    for (int r = 0; r < RPW; ++r) rm[r] = INFINITY;
#pragma unroll
    for (int r = 0; r < RPW; ++r) {
        for (int tt = 0; tt < 3; ++tt) {
            const int tb = (tc[r] + tt) * 256;
            const float4 q0 = pts[tb + lane];
            const float4 q1 = pts[tb + 64 + lane];
            const float4 q2 = pts[tb + 128 + lane];
            const float4 q3 = pts[tb + 192 + lane];
            const float d0 = (ss[r] + q0.w) - 2.0f * fmaf(zs[r], q0.z, fmaf(ys[r], q0.y, xs[r] * q0.x));
            const float d1 = (ss[r] + q1.w) - 2.0f * fmaf(zs[r], q1.z, fmaf(ys[r], q1.y, xs[r] * q1.x));
            const float d2 = (ss[r] + q2.w) - 2.0f * fmaf(zs[r], q2.z, fmaf(ys[r], q2.y, xs[r] * q2.x));
            const float d3 = (ss[r] + q3.w) - 2.0f * fmaf(zs[r], q3.z, fmaf(ys[r], q3.y, xs[r] * q3.x));
            rm[r] = fminf(rm[r], fminf(fminf(d0, d1), fminf(d2, d3)));
        }
    }
    // r12-verified bitonic sort of 64 lane-mins; tau = 17th (conservative:
    // 17 distinct sampled candidates have d2 <= tau -> C >= 17).
    float sv[RPW];
#pragma unroll
    for (int r = 0; r < RPW; ++r) sv[r] = rm[r];
#pragma unroll
    for (int k = 2; k <= 64; k <<= 1) {
#pragma unroll
        for (int j = k >> 1; j >= 1; j >>= 1) {
            const bool keepmin = (((lane & j) == 0) == ((lane & k) == 0));
#pragma unroll
            for (int r = 0; r < RPW; ++r) {
                const float o = __shfl_xor(sv[r], j);
                sv[r] = keepmin ? fminf(sv[r], o) : fmaxf(sv[r], o);
            }
        }
    }
    float tau[RPW];
#pragma unroll
    for (int r = 0; r < RPW; ++r)   // *1.000002+eps: sqrt-tie-collapse guard
        tau[r] = fmaxf(bcastf(sv[r], 16), 0.0f) * 1.000002f + 1e-30f;

    if (lane < RPW) cnt[wid][lane] = 0;
    asm volatile("s_waitcnt lgkmcnt(0)" ::: "memory");

    // ===== screen pass: AABB-pruned tiles (r15-r17-verified body) =====
    for (int t = 0; t < NT; ++t) {
        const float2 mm = tmm[t];
        bool kp[RPW]; bool anyk = false;
#pragma unroll
        for (int r = 0; r < RPW; ++r) {
            const float dx = fmaxf(fmaxf(mm.x - xs[r], xs[r] - mm.y), 0.0f);
            // prune slack: fp32 cancellation bound on ref-d2 vs true-d2
            kp[r] = (dx * dx <= tau[r] * 1.00001f + 5e-5f);
            anyk |= kp[r];
        }
        if (!anyk) continue;        // wave-uniform skip
        const int base = t * 256;
        const float4 q0 = pts[base + lane];
        const float4 q1 = pts[base + 64 + lane];
        const float4 q2 = pts[base + 128 + lane];
        const float4 q3 = pts[base + 192 + lane];
#pragma unroll
        for (int r = 0; r < RPW; ++r) {
            if (!kp[r]) continue;
            const float d0 = (ss[r] + q0.w) - 2.0f * fmaf(zs[r], q0.z, fmaf(ys[r], q0.y, xs[r] * q0.x));
            const float d1 = (ss[r] + q1.w) - 2.0f * fmaf(zs[r], q1.z, fmaf(ys[r], q1.y, xs[r] * q1.x));
            const float d2 = (ss[r] + q2.w) - 2.0f * fmaf(zs[r], q2.z, fmaf(ys[r], q2.y, xs[r] * q2.x));
            const float d3 = (ss[r] + q3.w) - 2.0f * fmaf(zs[r], q3.z, fmaf(ys[r], q3.y, xs[r] * q3.x));
            const bool p0 = d0 <= tau[r], p1 = d1 <= tau[r];
            const bool p2 = d2 <= tau[r], p3 = d3 <= tau[r];
            if (p0 | p1 | p2 | p3) {
                if (p0) { const int o = atomicAdd(&cnt[wid][r], 1);
                          if (o < CAP) buf[wid][r][o] = (((u64)__float_as_uint(fmaxf(d0, 0.f))) << 32) | (unsigned)(base + lane); }
                if (p1) { const int o = atomicAdd(&cnt[wid][r], 1);
                          if (o < CAP) buf[wid][r][o] = (((u64)__float_as_uint(fmaxf(d1, 0.f))) << 32) | (unsigned)(base + 64 + lane); }
                if (p2) { const int o = atomicAdd(&cnt[wid][r], 1);
                          if (o < CAP) buf[wid][r][o] = (((u64)__float_as_uint(fmaxf(d2, 0.f))) << 32) | (unsigned)(base + 128 + lane); }
                if (p3) { const int o = atomicAdd(&cnt[wid][r], 1);
                          if (o < CAP) buf[wid][r][o] = (((u64)__float_as_uint(fmaxf(d3, 0.f))) << 32) | (unsigned)(base + 192 + lane); }
            }
        }
    }
    asm volatile("s_waitcnt lgkmcnt(0)" ::: "memory");

    // ===== select + DIRECT ones-write (fill completed in prior dispatch) =====
#pragma unroll
    for (int r = 0; r < RPW; ++r) {
        const int C = cnt[wid][r];
        const int row = rowBase + wid * RPW + r;
        if (C <= CAP) {                 // C >= 17 guaranteed (tau subset bound)
            for (int e = lane; e < C; e += 64) {
                const u64 k2 = buf[wid][r][e];
                const float dd = sqrtf(__uint_as_float((unsigned)(k2 >> 32)));
                const int oi = perm[(int)(k2 & 0xffffffffu)];   // sorted -> orig
                buf[wid][r][e] = (((u64)__float_as_uint(dd)) << 32) | (unsigned)oi;
            }
            asm volatile("s_waitcnt lgkmcnt(0) vmcnt(0)" ::: "memory");
            for (int e = lane; e < C; e += 64) {
                const u64 my = buf[wid][r][e];
                int rk = 0;
                for (int c = 0; c < C; ++c)
                    rk += (buf[wid][r][c] < my) ? 1 : 0;   // orig idx unique
                if (rk >= 1 && rk <= KK)
                    out[(size_t)row * NN + (int)(my & 0xffffffffu)] = 1.0f;
            }
        } else {
            // Pathological overflow: verified full-scan insert, orig-idx keys.
            float ld = INFINITY; int li = 0x7fffffff;
            float td = INFINITY; int ti = 0x7fffffff; float t2 = INFINITY;
            for (int tt = 0; tt < NN / 64; ++tt) {
                const int j = tt * 64 + lane;
                const float4 q = pts[j];
                const int oi = perm[j];
                const float dd = (ss[r] + q.w) - 2.0f * fmaf(zs[r], q.z, fmaf(ys[r], q.y, xs[r] * q.x));
                insert_tile(dd <= t2, dd, oi, ld, li, td, ti, t2, lane);
            }
            if (lane >= 1 && lane <= KK)
                out[(size_t)row * NN + li] = 1.0f;
        }
    }
}

extern "C" void kernel_launch(void* const* d_in, const int* in_sizes, int n_in,
                              void* d_out, int out_size, void* d_ws, size_t ws_size,
                              hipStream_t stream) {
    const float* nodes = (const float*)d_in[0];
    float* out = (float*)d_out;
    (void)in_sizes; (void)n_in; (void)out_size; (void)ws_size;

    char* ws = (char*)d_ws;
    float4* pts  = (float4*)(ws + WS_PTS);
    int*    perm = (int*)   (ws + WS_PERM);
    int*    hist = (int*)   (ws + WS_HIST);
    int*    cur  = (int*)   (ws + WS_CUR);
    float2* tmm  = (float2*)(ws + WS_TMM);

    hipLaunchKernelGGL(zero_hist,     dim3(1),           dim3(NB),  0, stream, hist);
    hipLaunchKernelGGL(hist_kernel,   dim3(NN / 256),    dim3(256), 0, stream, nodes, hist);
    hipLaunchKernelGGL(scan_kernel,   dim3(1),           dim3(NB),  0, stream, hist, cur);
    hipLaunchKernelGGL(scatter_kernel,dim3(NN / 256),    dim3(256), 0, stream, nodes, cur, pts, perm);
    hipLaunchKernelGGL(bounds_kernel, dim3(NT),          dim3(256), 0, stream, pts, tmm);
    hipLaunchKernelGGL(fill_zero,     dim3(FILL_BLOCKS), dim3(256), 0, stream, (f32x4*)out);
    hipLaunchKernelGGL(knn_scan,      dim3(NN / RPB),    dim3(256), 0, stream,
                       pts, perm, cur, tmm, nodes, out);
}

// Round 19
// 767.609 us; speedup vs baseline: 1.3292x; 1.0555x over previous
//
#include <hip/hip_runtime.h>
#include <math.h>

#define NN 16384
#define KK 16
#define RPW 4                       // rows per scan wave
#define SW 4                        // scan waves per block
#define RPB (SW * RPW)              // 16 rows per block
#define CAP 128                     // per-row candidate buffer (u64 keys)
#define NB 1024                     // x-sort buckets
#define NT 64                       // tiles of 256 sorted points
#define FILL_BLOCKS 2048

typedef float f32x4 __attribute__((ext_vector_type(4)));
typedef unsigned long long u64;

// ---- d_ws layout (bytes): pts | perm | hist | cur | tileMM  (~338 KB) ----
#define WS_PTS   0
#define WS_PERM  (NN * 16)
#define WS_HIST  (WS_PERM + NN * 4)
#define WS_CUR   (WS_HIST + NB * 4)
#define WS_TMM   (WS_CUR + NB * 4)

// ---------------- sort pipeline (5 tiny kernels, r15-r18-verified) ----------
__global__ void zero_hist(int* __restrict__ hist) { hist[threadIdx.x] = 0; }

__device__ __forceinline__ int xbucket(float x) {
    int b = (int)((x + 6.0f) * (NB / 12.0f));
    return b < 0 ? 0 : (b > NB - 1 ? NB - 1 : b);
}

__global__ void hist_kernel(const float* __restrict__ nodes, int* __restrict__ hist) {
    const int i = blockIdx.x * 256 + threadIdx.x;
    atomicAdd(&hist[xbucket(nodes[3 * i])], 1);
}

__global__ void scan_kernel(const int* __restrict__ hist, int* __restrict__ cur) {
    __shared__ int s[NB];
    const int tid = threadIdx.x;
    const int h0 = hist[tid];
    s[tid] = h0; __syncthreads();
    for (int o = 1; o < NB; o <<= 1) {
        const int v = (tid >= o) ? s[tid - o] : 0;
        __syncthreads();
        s[tid] += v;
        __syncthreads();
    }
    cur[tid] = s[tid] - h0;     // exclusive prefix
}

__global__ void scatter_kernel(const float* __restrict__ nodes, int* __restrict__ cur,
                               float4* __restrict__ pts, int* __restrict__ perm) {
#pragma clang fp contract(off)
    const int i = blockIdx.x * 256 + threadIdx.x;
    const float x = nodes[3 * i], y = nodes[3 * i + 1], z = nodes[3 * i + 2];
    const float sq = (x * x + y * y) + z * z;     // reference arithmetic
    const int pos = atomicAdd(&cur[xbucket(x)], 1);
    pts[pos] = make_float4(x, y, z, sq);
    perm[pos] = i;
}
// after scatter, cur[b] = inclusive end position of bucket b (tile lookup)

__global__ void bounds_kernel(const float4* __restrict__ pts, float2* __restrict__ tmm) {
    __shared__ float mn[256], mx[256];
    const int tid = threadIdx.x;
    const float x = pts[blockIdx.x * 256 + tid].x;
    mn[tid] = x; mx[tid] = x; __syncthreads();
    for (int o = 128; o >= 1; o >>= 1) {
        if (tid < o) { mn[tid] = fminf(mn[tid], mn[tid + o]); mx[tid] = fmaxf(mx[tid], mx[tid + o]); }
        __syncthreads();
    }
    if (tid == 0) tmm[blockIdx.x] = make_float2(mn[0], mx[0]);
}

// ------- dedicated fill: NT streaming stores (r5-measured ~175 us, 6 TB/s).
// Plain cached stores throttle at the L2 write-allocate path (r18: 1.6 TB/s).
__global__ __launch_bounds__(256) void fill_zero(f32x4* __restrict__ ob) {
    const int tid = blockIdx.x * 256 + threadIdx.x;
    const int nthreads = FILL_BLOCKS * 256;
    const f32x4 z4 = {0.f, 0.f, 0.f, 0.f};
#pragma unroll 4
    for (int k = 0; k < (NN * (NN / 4)) / nthreads; ++k)   // 128 iterations
        __builtin_nontemporal_store(z4, ob + (size_t)k * nthreads + tid);
}

// ---------------- verified helpers ----------------
__device__ __forceinline__ float bcastf(float v, int l) {
    return __int_as_float(__builtin_amdgcn_readlane(__float_as_int(v), l));
}
__device__ __forceinline__ bool lexless(float da, int ia, float db, int ib) {
    return (da < db) || ((da == db) && (ia < ib));
}
// r1-r6-verified distributed insert — overflow fallback only.
__device__ __forceinline__ void insert_tile(bool rough, float d2, int j,
                                            float& ld, int& li,
                                            float& td, int& ti, float& td2u,
                                            int lane) {
#pragma clang fp contract(off)
    if (!__any(rough)) return;
    float dist = INFINITY;
    if (rough) dist = sqrtf(fmaxf(d2, 0.0f));
    bool done = false;
    while (true) {
        const bool pass = (!done) && rough && lexless(dist, j, td, ti);
        const u64 m = __ballot(pass);
        if (m == 0ull) break;
        const int src = __ffsll(m) - 1;
        const float dc = __shfl(dist, src);
        const int   ic = __shfl(j, src);
        if (lane == src) done = true;
        const bool gt = lexless(dc, ic, ld, li);
        const u64 gm = __ballot(gt);
        const int p = __ffsll(gm) - 1;
        const float pd = __shfl_up(ld, 1);
        const int   pi = __shfl_up(li, 1);
        if (gt) {
            if (lane == p) { ld = dc; li = ic; }
            else           { ld = pd; li = pi; }
        }
        td = __shfl(ld, 16);
        ti = __shfl(li, 16);
        td2u = td * td * 1.000001f;
    }
}

// ---------- dedicated scan: 4 scan waves x 4 rows; ones written directly ----
// Runs AFTER fill_zero on the stream -> stream order guarantees the zeros
// are complete and visible; no intra-kernel ordering tricks needed.
__global__ __launch_bounds__(256) void knn_scan(const float4* __restrict__ pts,
                                                const int* __restrict__ perm,
                                                const int* __restrict__ cur,
                                                const float2* __restrict__ tmm_g,
                                                const float* __restrict__ nodes,
                                                float* __restrict__ out) {
#pragma clang fp contract(off)
    const int lane = threadIdx.x & 63;
    const int wid  = threadIdx.x >> 6;
    const int tid  = threadIdx.x;
    const int rowBase = blockIdx.x * RPB;   // ORIGINAL row index, contiguous

    __shared__ float2 tmm[NT];
    __shared__ u64 buf[SW][RPW][CAP];
    __shared__ int cnt[SW][RPW];

    if (tid < NT) tmm[tid] = tmm_g[tid];
    __syncthreads();

    // ---- per-row setup (reference arithmetic) + home-tile lookup ----
    float xs[RPW], ys[RPW], zs[RPW], ss[RPW];
    int tc[RPW];
#pragma unroll
    for (int r = 0; r < RPW; ++r) {
        const int row = rowBase + wid * RPW + r;
        xs[r] = nodes[3 * row];
        ys[r] = nodes[3 * row + 1];
        zs[r] = nodes[3 * row + 2];
        ss[r] = (xs[r] * xs[r] + ys[r] * ys[r]) + zs[r] * zs[r];
        int t = (cur[xbucket(xs[r])] - 1) >> 8;
        t = t - 1; t = t < 0 ? 0 : (t > NT - 3 ? NT - 3 : t);
        tc[r] = t;
    }

    // ===== tau phase: 3 local tiles per row (768 actual candidates) =====
    float rm[RPW];
#pragma unroll
    for (int r = 0; r < RPW; ++r) rm[r] = INFINITY;
#pragma unroll
    for (int r = 0; r < RPW; ++r) {
        for (int tt = 0; tt < 3; ++tt) {
            const int tb = (tc[r] + tt) * 256;
            const float4 q0 = pts[tb + lane];
            const float4 q1 = pts[tb + 64 + lane];
            const float4 q2 = pts[tb + 128 + lane];
            const float4 q3 = pts[tb + 192 + lane];
            const float d0 = (ss[r] + q0.w) - 2.0f * fmaf(zs[r], q0.z, fmaf(ys[r], q0.y, xs[r] * q0.x));
            const float d1 = (ss[r] + q1.w) - 2.0f * fmaf(zs[r], q1.z, fmaf(ys[r], q1.y, xs[r] * q1.x));
            const float d2 = (ss[r] + q2.w) - 2.0f * fmaf(zs[r], q2.z, fmaf(ys[r], q2.y, xs[r] * q2.x));
            const float d3 = (ss[r] + q3.w) - 2.0f * fmaf(zs[r], q3.z, fmaf(ys[r], q3.y, xs[r] * q3.x));
            rm[r] = fminf(rm[r], fminf(fminf(d0, d1), fminf(d2, d3)));
        }
    }
    // r12-verified bitonic sort of 64 lane-mins; tau = 17th (conservative:
    // 17 distinct sampled candidates have d2 <= tau -> C >= 17).
    float sv[RPW];
#pragma unroll
    for (int r = 0; r < RPW; ++r) sv[r] = rm[r];
#pragma unroll
    for (int k = 2; k <= 64; k <<= 1) {
#pragma unroll
        for (int j = k >> 1; j >= 1; j >>= 1) {
            const bool keepmin = (((lane & j) == 0) == ((lane & k) == 0));
#pragma unroll
            for (int r = 0; r < RPW; ++r) {
                const float o = __shfl_xor(sv[r], j);
                sv[r] = keepmin ? fminf(sv[r], o) : fmaxf(sv[r], o);
            }
        }
    }
    float tau[RPW];
#pragma unroll
    for (int r = 0; r < RPW; ++r)   // *1.000002+eps: sqrt-tie-collapse guard
        tau[r] = fmaxf(bcastf(sv[r], 16), 0.0f) * 1.000002f + 1e-30f;

    if (lane < RPW) cnt[wid][lane] = 0;
    asm volatile("s_waitcnt lgkmcnt(0)" ::: "memory");

    // ===== screen pass: AABB-pruned tiles (r15-r18-verified body) =====
    for (int t = 0; t < NT; ++t) {
        const float2 mm = tmm[t];
        bool kp[RPW]; bool anyk = false;
#pragma unroll
        for (int r = 0; r < RPW; ++r) {
            const float dx = fmaxf(fmaxf(mm.x - xs[r], xs[r] - mm.y), 0.0f);
            // prune slack: fp32 cancellation bound on ref-d2 vs true-d2
            kp[r] = (dx * dx <= tau[r] * 1.00001f + 5e-5f);
            anyk |= kp[r];
        }
        if (!anyk) continue;        // wave-uniform skip
        const int base = t * 256;
        const float4 q0 = pts[base + lane];
        const float4 q1 = pts[base + 64 + lane];
        const float4 q2 = pts[base + 128 + lane];
        const float4 q3 = pts[base + 192 + lane];
#pragma unroll
        for (int r = 0; r < RPW; ++r) {
            if (!kp[r]) continue;
            const float d0 = (ss[r] + q0.w) - 2.0f * fmaf(zs[r], q0.z, fmaf(ys[r], q0.y, xs[r] * q0.x));
            const float d1 = (ss[r] + q1.w) - 2.0f * fmaf(zs[r], q1.z, fmaf(ys[r], q1.y, xs[r] * q1.x));
            const float d2 = (ss[r] + q2.w) - 2.0f * fmaf(zs[r], q2.z, fmaf(ys[r], q2.y, xs[r] * q2.x));
            const float d3 = (ss[r] + q3.w) - 2.0f * fmaf(zs[r], q3.z, fmaf(ys[r], q3.y, xs[r] * q3.x));
            const bool p0 = d0 <= tau[r], p1 = d1 <= tau[r];
            const bool p2 = d2 <= tau[r], p3 = d3 <= tau[r];
            if (p0 | p1 | p2 | p3) {
                if (p0) { const int o = atomicAdd(&cnt[wid][r], 1);
                          if (o < CAP) buf[wid][r][o] = (((u64)__float_as_uint(fmaxf(d0, 0.f))) << 32) | (unsigned)(base + lane); }
                if (p1) { const int o = atomicAdd(&cnt[wid][r], 1);
                          if (o < CAP) buf[wid][r][o] = (((u64)__float_as_uint(fmaxf(d1, 0.f))) << 32) | (unsigned)(base + 64 + lane); }
                if (p2) { const int o = atomicAdd(&cnt[wid][r], 1);
                          if (o < CAP) buf[wid][r][o] = (((u64)__float_as_uint(fmaxf(d2, 0.f))) << 32) | (unsigned)(base + 128 + lane); }
                if (p3) { const int o = atomicAdd(&cnt[wid][r], 1);
                          if (o < CAP) buf[wid][r][o] = (((u64)__float_as_uint(fmaxf(d3, 0.f))) << 32) | (unsigned)(base + 192 + lane); }
            }
        }
    }
    asm volatile("s_waitcnt lgkmcnt(0)" ::: "memory");

    // ===== select + DIRECT ones-write (fill completed in prior dispatch) =====
#pragma unroll
    for (int r = 0; r < RPW; ++r) {
        const int C = cnt[wid][r];
        const int row = rowBase + wid * RPW + r;
        if (C <= CAP) {                 // C >= 17 guaranteed (tau subset bound)
            for (int e = lane; e < C; e += 64) {
                const u64 k2 = buf[wid][r][e];
                const float dd = sqrtf(__uint_as_float((unsigned)(k2 >> 32)));
                const int oi = perm[(int)(k2 & 0xffffffffu)];   // sorted -> orig
                buf[wid][r][e] = (((u64)__float_as_uint(dd)) << 32) | (unsigned)oi;
            }
            asm volatile("s_waitcnt lgkmcnt(0) vmcnt(0)" ::: "memory");
            for (int e = lane; e < C; e += 64) {
                const u64 my = buf[wid][r][e];
                int rk = 0;
                for (int c = 0; c < C; ++c)
                    rk += (buf[wid][r][c] < my) ? 1 : 0;   // orig idx unique
                if (rk >= 1 && rk <= KK)
                    out[(size_t)row * NN + (int)(my & 0xffffffffu)] = 1.0f;
            }
        } else {
            // Pathological overflow: verified full-scan insert, orig-idx keys.
            float ld = INFINITY; int li = 0x7fffffff;
            float td = INFINITY; int ti = 0x7fffffff; float t2 = INFINITY;
            for (int tt = 0; tt < NN / 64; ++tt) {
                const int j = tt * 64 + lane;
                const float4 q = pts[j];
                const int oi = perm[j];
                const float dd = (ss[r] + q.w) - 2.0f * fmaf(zs[r], q.z, fmaf(ys[r], q.y, xs[r] * q.x));
                insert_tile(dd <= t2, dd, oi, ld, li, td, ti, t2, lane);
            }
            if (lane >= 1 && lane <= KK)
                out[(size_t)row * NN + li] = 1.0f;
        }
    }
}

extern "C" void kernel_launch(void* const* d_in, const int* in_sizes, int n_in,
                              void* d_out, int out_size, void* d_ws, size_t ws_size,
                              hipStream_t stream) {
    const float* nodes = (const float*)d_in[0];
    float* out = (float*)d_out;
    (void)in_sizes; (void)n_in; (void)out_size; (void)ws_size;

    char* ws = (char*)d_ws;
    float4* pts  = (float4*)(ws + WS_PTS);
    int*    perm = (int*)   (ws + WS_PERM);
    int*    hist = (int*)   (ws + WS_HIST);
    int*    cur  = (int*)   (ws + WS_CUR);
    float2* tmm  = (float2*)(ws + WS_TMM);

    hipLaunchKernelGGL(zero_hist,     dim3(1),           dim3(NB),  0, stream, hist);
    hipLaunchKernelGGL(hist_kernel,   dim3(NN / 256),    dim3(256), 0, stream, nodes, hist);
    hipLaunchKernelGGL(scan_kernel,   dim3(1),           dim3(NB),  0, stream, hist, cur);
    hipLaunchKernelGGL(scatter_kernel,dim3(NN / 256),    dim3(256), 0, stream, nodes, cur, pts, perm);
    hipLaunchKernelGGL(bounds_kernel, dim3(NT),          dim3(256), 0, stream, pts, tmm);
    hipLaunchKernelGGL(fill_zero,     dim3(FILL_BLOCKS), dim3(256), 0, stream, (f32x4*)out);
    hipLaunchKernelGGL(knn_scan,      dim3(NN / RPB),    dim3(256), 0, stream,
                       pts, perm, cur, tmm, nodes, out);
}

// Round 20
// 416.754 us; speedup vs baseline: 2.4482x; 1.8419x over previous
//
#include <hip/hip_runtime.h>
#include <math.h>

#define NN 16384
#define KK 16
#define RPW 4                       // rows per scan wave
#define SW 4                        // scan waves per block
#define RPB (SW * RPW)              // 16 rows per block
#define CAP 512                     // per-row candidate buffer (u16 sorted idx)
#define NB 1024                     // x-sort buckets
#define NT 64                       // tiles of 256 sorted points
#define FILL_BLOCKS 2048

typedef float f32x4 __attribute__((ext_vector_type(4)));
typedef unsigned long long u64;
typedef unsigned short u16;

// ---- d_ws layout (bytes): pts | perm | hist | cur | tileMM  (~338 KB) ----
#define WS_PTS   0
#define WS_PERM  (NN * 16)
#define WS_HIST  (WS_PERM + NN * 4)
#define WS_CUR   (WS_HIST + NB * 4)
#define WS_TMM   (WS_CUR + NB * 4)

// ---------------- sort pipeline (5 tiny kernels, r15-r19-verified) ----------
__global__ void zero_hist(int* __restrict__ hist) { hist[threadIdx.x] = 0; }

__device__ __forceinline__ int xbucket(float x) {
    int b = (int)((x + 6.0f) * (NB / 12.0f));
    return b < 0 ? 0 : (b > NB - 1 ? NB - 1 : b);
}

__global__ void hist_kernel(const float* __restrict__ nodes, int* __restrict__ hist) {
    const int i = blockIdx.x * 256 + threadIdx.x;
    atomicAdd(&hist[xbucket(nodes[3 * i])], 1);
}

__global__ void scan_kernel(const int* __restrict__ hist, int* __restrict__ cur) {
    __shared__ int s[NB];
    const int tid = threadIdx.x;
    const int h0 = hist[tid];
    s[tid] = h0; __syncthreads();
    for (int o = 1; o < NB; o <<= 1) {
        const int v = (tid >= o) ? s[tid - o] : 0;
        __syncthreads();
        s[tid] += v;
        __syncthreads();
    }
    cur[tid] = s[tid] - h0;     // exclusive prefix
}

__global__ void scatter_kernel(const float* __restrict__ nodes, int* __restrict__ cur,
                               float4* __restrict__ pts, int* __restrict__ perm) {
#pragma clang fp contract(off)
    const int i = blockIdx.x * 256 + threadIdx.x;
    const float x = nodes[3 * i], y = nodes[3 * i + 1], z = nodes[3 * i + 2];
    const float sq = (x * x + y * y) + z * z;     // reference arithmetic
    const int pos = atomicAdd(&cur[xbucket(x)], 1);
    pts[pos] = make_float4(x, y, z, sq);
    perm[pos] = i;
}
// after scatter, cur[b] = inclusive end position of bucket b (tile lookup)

__global__ void bounds_kernel(const float4* __restrict__ pts, float2* __restrict__ tmm) {
    __shared__ float mn[256], mx[256];
    const int tid = threadIdx.x;
    const float x = pts[blockIdx.x * 256 + tid].x;
    mn[tid] = x; mx[tid] = x; __syncthreads();
    for (int o = 128; o >= 1; o >>= 1) {
        if (tid < o) { mn[tid] = fminf(mn[tid], mn[tid + o]); mx[tid] = fmaxf(mx[tid], mx[tid + o]); }
        __syncthreads();
    }
    if (tid == 0) tmm[blockIdx.x] = make_float2(mn[0], mx[0]);
}

// ------- dedicated fill: NT streaming stores (r5-measured fast path) -------
__global__ __launch_bounds__(256) void fill_zero(f32x4* __restrict__ ob) {
    const int tid = blockIdx.x * 256 + threadIdx.x;
    const int nthreads = FILL_BLOCKS * 256;
    const f32x4 z4 = {0.f, 0.f, 0.f, 0.f};
#pragma unroll 4
    for (int k = 0; k < (NN * (NN / 4)) / nthreads; ++k)   // 128 iterations
        __builtin_nontemporal_store(z4, ob + (size_t)k * nthreads + tid);
}

// ---------------- verified helpers ----------------
__device__ __forceinline__ float bcastf(float v, int l) {
    return __int_as_float(__builtin_amdgcn_readlane(__float_as_int(v), l));
}
__device__ __forceinline__ bool lexless(float da, int ia, float db, int ib) {
    return (da < db) || ((da == db) && (ia < ib));
}
// r1-r6-verified distributed insert — overflow fallback only (now ~never hit).
__device__ __forceinline__ void insert_tile(bool rough, float d2, int j,
                                            float& ld, int& li,
                                            float& td, int& ti, float& td2u,
                                            int lane) {
#pragma clang fp contract(off)
    if (!__any(rough)) return;
    float dist = INFINITY;
    if (rough) dist = sqrtf(fmaxf(d2, 0.0f));
    bool done = false;
    while (true) {
        const bool pass = (!done) && rough && lexless(dist, j, td, ti);
        const u64 m = __ballot(pass);
        if (m == 0ull) break;
        const int src = __ffsll(m) - 1;
        const float dc = __shfl(dist, src);
        const int   ic = __shfl(j, src);
        if (lane == src) done = true;
        const bool gt = lexless(dc, ic, ld, li);
        const u64 gm = __ballot(gt);
        const int p = __ffsll(gm) - 1;
        const float pd = __shfl_up(ld, 1);
        const int   pi = __shfl_up(li, 1);
        if (gt) {
            if (lane == p) { ld = dc; li = ic; }
            else           { ld = pd; li = pi; }
        }
        td = __shfl(ld, 16);
        ti = __shfl(li, 16);
        td2u = td * td * 1.000001f;
    }
}

// ---------- dedicated scan: 4 scan waves x 4 rows; ones written directly ----
// Runs AFTER fill_zero on the stream -> stream order guarantees zeros done.
__global__ __launch_bounds__(256) void knn_scan(const float4* __restrict__ pts,
                                                const int* __restrict__ perm,
                                                const int* __restrict__ cur,
                                                const float2* __restrict__ tmm_g,
                                                const float* __restrict__ nodes,
                                                float* __restrict__ out) {
#pragma clang fp contract(off)
    const int lane = threadIdx.x & 63;
    const int wid  = threadIdx.x >> 6;
    const int tid  = threadIdx.x;
    const int rowBase = blockIdx.x * RPB;   // ORIGINAL row index, contiguous

    __shared__ float2 tmm[NT];
    __shared__ u16 buf[SW][RPW][CAP];       // 16 KB: candidate sorted-indices
    __shared__ u64 sel[SW][CAP];            // 16 KB: (distbits, orig idx) keys
    __shared__ int cnt[SW][RPW];

    if (tid < NT) tmm[tid] = tmm_g[tid];
    __syncthreads();

    // ---- per-row setup (reference arithmetic) + home-tile lookup ----
    float xs[RPW], ys[RPW], zs[RPW], ss[RPW];
    int tc[RPW];
#pragma unroll
    for (int r = 0; r < RPW; ++r) {
        const int row = rowBase + wid * RPW + r;
        xs[r] = nodes[3 * row];
        ys[r] = nodes[3 * row + 1];
        zs[r] = nodes[3 * row + 2];
        ss[r] = (xs[r] * xs[r] + ys[r] * ys[r]) + zs[r] * zs[r];
        int t = (cur[xbucket(xs[r])] - 1) >> 8;
        t = t - 1; t = t < 0 ? 0 : (t > NT - 3 ? NT - 3 : t);
        tc[r] = t;
    }

    // ===== tau phase: 3 local tiles per row (768 actual candidates) =====
    float rm[RPW];
#pragma unroll
    for (int r = 0; r < RPW; ++r) rm[r] = INFINITY;
#pragma unroll
    for (int r = 0; r < RPW; ++r) {
        for (int tt = 0; tt < 3; ++tt) {
            const int tb = (tc[r] + tt) * 256;
            const float4 q0 = pts[tb + lane];
            const float4 q1 = pts[tb + 64 + lane];
            const float4 q2 = pts[tb + 128 + lane];
            const float4 q3 = pts[tb + 192 + lane];
            const float d0 = (ss[r] + q0.w) - 2.0f * fmaf(zs[r], q0.z, fmaf(ys[r], q0.y, xs[r] * q0.x));
            const float d1 = (ss[r] + q1.w) - 2.0f * fmaf(zs[r], q1.z, fmaf(ys[r], q1.y, xs[r] * q1.x));
            const float d2 = (ss[r] + q2.w) - 2.0f * fmaf(zs[r], q2.z, fmaf(ys[r], q2.y, xs[r] * q2.x));
            const float d3 = (ss[r] + q3.w) - 2.0f * fmaf(zs[r], q3.z, fmaf(ys[r], q3.y, xs[r] * q3.x));
            rm[r] = fminf(rm[r], fminf(fminf(d0, d1), fminf(d2, d3)));
        }
    }
    // r12-verified bitonic sort of 64 lane-mins; tau = 17th (conservative:
    // 17 distinct sampled candidates have d2 <= tau -> C >= 17).
    float sv[RPW];
#pragma unroll
    for (int r = 0; r < RPW; ++r) sv[r] = rm[r];
#pragma unroll
    for (int k = 2; k <= 64; k <<= 1) {
#pragma unroll
        for (int j = k >> 1; j >= 1; j >>= 1) {
            const bool keepmin = (((lane & j) == 0) == ((lane & k) == 0));
#pragma unroll
            for (int r = 0; r < RPW; ++r) {
                const float o = __shfl_xor(sv[r], j);
                sv[r] = keepmin ? fminf(sv[r], o) : fmaxf(sv[r], o);
            }
        }
    }
    float tau[RPW];
#pragma unroll
    for (int r = 0; r < RPW; ++r)   // *1.000002+eps: sqrt-tie-collapse guard
        tau[r] = fmaxf(bcastf(sv[r], 16), 0.0f) * 1.000002f + 1e-30f;

    if (lane < RPW) cnt[wid][lane] = 0;
    asm volatile("s_waitcnt lgkmcnt(0)" ::: "memory");

    // ===== screen pass: AABB-pruned tiles; append u16 sorted-idx only =====
    for (int t = 0; t < NT; ++t) {
        const float2 mm = tmm[t];
        bool kp[RPW]; bool anyk = false;
#pragma unroll
        for (int r = 0; r < RPW; ++r) {
            const float dx = fmaxf(fmaxf(mm.x - xs[r], xs[r] - mm.y), 0.0f);
            // prune slack: fp32 cancellation bound on ref-d2 vs true-d2
            kp[r] = (dx * dx <= tau[r] * 1.00001f + 5e-5f);
            anyk |= kp[r];
        }
        if (!anyk) continue;        // wave-uniform skip
        const int base = t * 256;
        const float4 q0 = pts[base + lane];
        const float4 q1 = pts[base + 64 + lane];
        const float4 q2 = pts[base + 128 + lane];
        const float4 q3 = pts[base + 192 + lane];
#pragma unroll
        for (int r = 0; r < RPW; ++r) {
            if (!kp[r]) continue;
            const float d0 = (ss[r] + q0.w) - 2.0f * fmaf(zs[r], q0.z, fmaf(ys[r], q0.y, xs[r] * q0.x));
            const float d1 = (ss[r] + q1.w) - 2.0f * fmaf(zs[r], q1.z, fmaf(ys[r], q1.y, xs[r] * q1.x));
            const float d2 = (ss[r] + q2.w) - 2.0f * fmaf(zs[r], q2.z, fmaf(ys[r], q2.y, xs[r] * q2.x));
            const float d3 = (ss[r] + q3.w) - 2.0f * fmaf(zs[r], q3.z, fmaf(ys[r], q3.y, xs[r] * q3.x));
            const bool p0 = d0 <= tau[r], p1 = d1 <= tau[r];
            const bool p2 = d2 <= tau[r], p3 = d3 <= tau[r];
            if (p0 | p1 | p2 | p3) {
                if (p0) { const int o = atomicAdd(&cnt[wid][r], 1);
                          if (o < CAP) buf[wid][r][o] = (u16)(base + lane); }
                if (p1) { const int o = atomicAdd(&cnt[wid][r], 1);
                          if (o < CAP) buf[wid][r][o] = (u16)(base + 64 + lane); }
                if (p2) { const int o = atomicAdd(&cnt[wid][r], 1);
                          if (o < CAP) buf[wid][r][o] = (u16)(base + 128 + lane); }
                if (p3) { const int o = atomicAdd(&cnt[wid][r], 1);
                          if (o < CAP) buf[wid][r][o] = (u16)(base + 192 + lane); }
            }
        }
    }
    asm volatile("s_waitcnt lgkmcnt(0)" ::: "memory");

    // ===== select: recompute d2 (ref arithmetic, r13-verified), exact
    // lex-(dist, ORIGINAL idx) rank (r14-verified), direct ones-write =====
#pragma unroll
    for (int r = 0; r < RPW; ++r) {
        const int C = cnt[wid][r];
        const int row = rowBase + wid * RPW + r;
        if (C <= CAP) {                 // C >= 17 guaranteed (tau subset bound)
            for (int e = lane; e < C; e += 64) {
                const int si = (int)buf[wid][r][e];
                const float4 q = pts[si];
                const float dd = (ss[r] + q.w) - 2.0f * fmaf(zs[r], q.z, fmaf(ys[r], q.y, xs[r] * q.x));
                const float dist = sqrtf(fmaxf(dd, 0.0f));      // IEEE, as ref
                sel[wid][e] = (((u64)__float_as_uint(dist)) << 32) | (unsigned)perm[si];
            }
            asm volatile("s_waitcnt lgkmcnt(0) vmcnt(0)" ::: "memory");
            for (int e = lane; e < C; e += 64) {
                const u64 my = sel[wid][e];
                int rk = 0;
                for (int c = 0; c < C; ++c)
                    rk += (sel[wid][c] < my) ? 1 : 0;   // orig idx unique
                if (rk >= 1 && rk <= KK)
                    out[(size_t)row * NN + (int)(my & 0xffffffffu)] = 1.0f;
            }
            asm volatile("s_waitcnt lgkmcnt(0)" ::: "memory");  // before sel reuse
        } else {
            // Pathological overflow: verified full-scan insert, orig-idx keys.
            float ld = INFINITY; int li = 0x7fffffff;
            float td = INFINITY; int ti = 0x7fffffff; float t2 = INFINITY;
            for (int tt = 0; tt < NN / 64; ++tt) {
                const int j = tt * 64 + lane;
                const float4 q = pts[j];
                const int oi = perm[j];
                const float dd = (ss[r] + q.w) - 2.0f * fmaf(zs[r], q.z, fmaf(ys[r], q.y, xs[r] * q.x));
                insert_tile(dd <= t2, dd, oi, ld, li, td, ti, t2, lane);
            }
            if (lane >= 1 && lane <= KK)
                out[(size_t)row * NN + li] = 1.0f;
        }
    }
}

extern "C" void kernel_launch(void* const* d_in, const int* in_sizes, int n_in,
                              void* d_out, int out_size, void* d_ws, size_t ws_size,
                              hipStream_t stream) {
    const float* nodes = (const float*)d_in[0];
    float* out = (float*)d_out;
    (void)in_sizes; (void)n_in; (void)out_size; (void)ws_size;

    char* ws = (char*)d_ws;
    float4* pts  = (float4*)(ws + WS_PTS);
    int*    perm = (int*)   (ws + WS_PERM);
    int*    hist = (int*)   (ws + WS_HIST);
    int*    cur  = (int*)   (ws + WS_CUR);
    float2* tmm  = (float2*)(ws + WS_TMM);

    hipLaunchKernelGGL(zero_hist,     dim3(1),           dim3(NB),  0, stream, hist);
    hipLaunchKernelGGL(hist_kernel,   dim3(NN / 256),    dim3(256), 0, stream, nodes, hist);
    hipLaunchKernelGGL(scan_kernel,   dim3(1),           dim3(NB),  0, stream, hist, cur);
    hipLaunchKernelGGL(scatter_kernel,dim3(NN / 256),    dim3(256), 0, stream, nodes, cur, pts, perm);
    hipLaunchKernelGGL(bounds_kernel, dim3(NT),          dim3(256), 0, stream, pts, tmm);
    hipLaunchKernelGGL(fill_zero,     dim3(FILL_BLOCKS), dim3(256), 0, stream, (f32x4*)out);
    hipLaunchKernelGGL(knn_scan,      dim3(NN / RPB),    dim3(256), 0, stream,
                       pts, perm, cur, tmm, nodes, out);
}

// Round 21
// 304.339 us; speedup vs baseline: 3.3526x; 1.3694x over previous
//
#include <hip/hip_runtime.h>
#include <math.h>

#define NN 16384
#define KK 16
#define RPW 4                       // rows per scan wave
#define SW 4                        // scan waves per block
#define RPB (SW * RPW)              // 16 rows per block
#define CAP 512                     // per-row candidate buffer (u16 sorted idx)
#define NB 1024                     // x-sort buckets
#define NT 64                       // tiles of 256 sorted points
#define FILL_BLOCKS 2048
#define SCAN_BLOCKS (NN / RPB)      // 1024

typedef float f32x4 __attribute__((ext_vector_type(4)));
typedef unsigned long long u64;
typedef unsigned short u16;

// ---- d_ws layout (bytes): pts | perm | hist | cur | tileMM | nb  ----
#define WS_PTS   0
#define WS_PERM  (NN * 16)
#define WS_HIST  (WS_PERM + NN * 4)
#define WS_CUR   (WS_HIST + NB * 4)
#define WS_TMM   (WS_CUR + NB * 4)
#define WS_NB    (WS_TMM + NT * 8)
#define WS_NEED  (WS_NB + (size_t)NN * KK * 2)

// ---------------- sort pipeline (5 tiny kernels, r15-r20-verified) ----------
__global__ void zero_hist(int* __restrict__ hist) { hist[threadIdx.x] = 0; }

__device__ __forceinline__ int xbucket(float x) {
    int b = (int)((x + 6.0f) * (NB / 12.0f));
    return b < 0 ? 0 : (b > NB - 1 ? NB - 1 : b);
}

__global__ void hist_kernel(const float* __restrict__ nodes, int* __restrict__ hist) {
    const int i = blockIdx.x * 256 + threadIdx.x;
    atomicAdd(&hist[xbucket(nodes[3 * i])], 1);
}

__global__ void scan_kernel(const int* __restrict__ hist, int* __restrict__ cur) {
    __shared__ int s[NB];
    const int tid = threadIdx.x;
    const int h0 = hist[tid];
    s[tid] = h0; __syncthreads();
    for (int o = 1; o < NB; o <<= 1) {
        const int v = (tid >= o) ? s[tid - o] : 0;
        __syncthreads();
        s[tid] += v;
        __syncthreads();
    }
    cur[tid] = s[tid] - h0;     // exclusive prefix
}

__global__ void scatter_kernel(const float* __restrict__ nodes, int* __restrict__ cur,
                               float4* __restrict__ pts, int* __restrict__ perm) {
#pragma clang fp contract(off)
    const int i = blockIdx.x * 256 + threadIdx.x;
    const float x = nodes[3 * i], y = nodes[3 * i + 1], z = nodes[3 * i + 2];
    const float sq = (x * x + y * y) + z * z;     // reference arithmetic
    const int pos = atomicAdd(&cur[xbucket(x)], 1);
    pts[pos] = make_float4(x, y, z, sq);
    perm[pos] = i;
}
// after scatter, cur[b] = inclusive end position of bucket b (tile lookup)

__global__ void bounds_kernel(const float4* __restrict__ pts, float2* __restrict__ tmm) {
    __shared__ float mn[256], mx[256];
    const int tid = threadIdx.x;
    const float x = pts[blockIdx.x * 256 + tid].x;
    mn[tid] = x; mx[tid] = x; __syncthreads();
    for (int o = 128; o >= 1; o >>= 1) {
        if (tid < o) { mn[tid] = fminf(mn[tid], mn[tid + o]); mx[tid] = fmaxf(mx[tid], mx[tid + o]); }
        __syncthreads();
    }
    if (tid == 0) tmm[blockIdx.x] = make_float2(mn[0], mx[0]);
}

// ---------------- verified helpers ----------------
__device__ __forceinline__ float bcastf(float v, int l) {
    return __int_as_float(__builtin_amdgcn_readlane(__float_as_int(v), l));
}
__device__ __forceinline__ bool lexless(float da, int ia, float db, int ib) {
    return (da < db) || ((da == db) && (ia < ib));
}
// r1-r6-verified distributed insert — overflow fallback only (~never hit).
__device__ __forceinline__ void insert_tile(bool rough, float d2, int j,
                                            float& ld, int& li,
                                            float& td, int& ti, float& td2u,
                                            int lane) {
#pragma clang fp contract(off)
    if (!__any(rough)) return;
    float dist = INFINITY;
    if (rough) dist = sqrtf(fmaxf(d2, 0.0f));
    bool done = false;
    while (true) {
        const bool pass = (!done) && rough && lexless(dist, j, td, ti);
        const u64 m = __ballot(pass);
        if (m == 0ull) break;
        const int src = __ffsll(m) - 1;
        const float dc = __shfl(dist, src);
        const int   ic = __shfl(j, src);
        if (lane == src) done = true;
        const bool gt = lexless(dc, ic, ld, li);
        const u64 gm = __ballot(gt);
        const int p = __ffsll(gm) - 1;
        const float pd = __shfl_up(ld, 1);
        const int   pi = __shfl_up(li, 1);
        if (gt) {
            if (lane == p) { ld = dc; li = ic; }
            else           { ld = pd; li = pi; }
        }
        td = __shfl(ld, 16);
        ti = __shfl(li, 16);
        td2u = td * td * 1.000001f;
    }
}

// ---------- scan body (r20-verified machinery; write target switchable) ----
// nbws != nullptr -> deposit u16 orig-idx neighbors (mega path, no out writes);
// nbws == nullptr -> direct 1.0 writes to out (r20 fallback path).
__device__ __forceinline__ void scan_body(int sblock,
                                          const float4* __restrict__ pts,
                                          const int* __restrict__ perm,
                                          const int* __restrict__ cur,
                                          const float2* __restrict__ tmm_g,
                                          const float* __restrict__ nodes,
                                          float* __restrict__ out,
                                          u16* __restrict__ nbws) {
#pragma clang fp contract(off)
    const int lane = threadIdx.x & 63;
    const int wid  = threadIdx.x >> 6;
    const int tid  = threadIdx.x;
    const int rowBase = sblock * RPB;       // ORIGINAL row index, contiguous

    __shared__ float2 tmm[NT];
    __shared__ u16 buf[SW][RPW][CAP];       // 16 KB: candidate sorted-indices
    __shared__ u64 sel[SW][CAP];            // 16 KB: (distbits, orig idx) keys
    __shared__ int cnt[SW][RPW];

    if (tid < NT) tmm[tid] = tmm_g[tid];
    __syncthreads();

    // ---- per-row setup (reference arithmetic) + home-tile lookup ----
    float xs[RPW], ys[RPW], zs[RPW], ss[RPW];
    int tc[RPW];
#pragma unroll
    for (int r = 0; r < RPW; ++r) {
        const int row = rowBase + wid * RPW + r;
        xs[r] = nodes[3 * row];
        ys[r] = nodes[3 * row + 1];
        zs[r] = nodes[3 * row + 2];
        ss[r] = (xs[r] * xs[r] + ys[r] * ys[r]) + zs[r] * zs[r];
        int t = (cur[xbucket(xs[r])] - 1) >> 8;
        t = t - 1; t = t < 0 ? 0 : (t > NT - 3 ? NT - 3 : t);
        tc[r] = t;
    }

    // ===== tau phase: 3 local tiles per row (768 actual candidates) =====
    float rm[RPW];
#pragma unroll
    for (int r = 0; r < RPW; ++r) rm[r] = INFINITY;
#pragma unroll
    for (int r = 0; r < RPW; ++r) {
        for (int tt = 0; tt < 3; ++tt) {
            const int tb = (tc[r] + tt) * 256;
            const float4 q0 = pts[tb + lane];
            const float4 q1 = pts[tb + 64 + lane];
            const float4 q2 = pts[tb + 128 + lane];
            const float4 q3 = pts[tb + 192 + lane];
            const float d0 = (ss[r] + q0.w) - 2.0f * fmaf(zs[r], q0.z, fmaf(ys[r], q0.y, xs[r] * q0.x));
            const float d1 = (ss[r] + q1.w) - 2.0f * fmaf(zs[r], q1.z, fmaf(ys[r], q1.y, xs[r] * q1.x));
            const float d2 = (ss[r] + q2.w) - 2.0f * fmaf(zs[r], q2.z, fmaf(ys[r], q2.y, xs[r] * q2.x));
            const float d3 = (ss[r] + q3.w) - 2.0f * fmaf(zs[r], q3.z, fmaf(ys[r], q3.y, xs[r] * q3.x));
            rm[r] = fminf(rm[r], fminf(fminf(d0, d1), fminf(d2, d3)));
        }
    }
    // r12-verified bitonic sort of 64 lane-mins; tau = 17th (conservative:
    // 17 distinct sampled candidates have d2 <= tau -> C >= 17).
    float sv[RPW];
#pragma unroll
    for (int r = 0; r < RPW; ++r) sv[r] = rm[r];
#pragma unroll
    for (int k = 2; k <= 64; k <<= 1) {
#pragma unroll
        for (int j = k >> 1; j >= 1; j >>= 1) {
            const bool keepmin = (((lane & j) == 0) == ((lane & k) == 0));
#pragma unroll
            for (int r = 0; r < RPW; ++r) {
                const float o = __shfl_xor(sv[r], j);
                sv[r] = keepmin ? fminf(sv[r], o) : fmaxf(sv[r], o);
            }
        }
    }
    float tau[RPW];
#pragma unroll
    for (int r = 0; r < RPW; ++r)   // *1.000002+eps: sqrt-tie-collapse guard
        tau[r] = fmaxf(bcastf(sv[r], 16), 0.0f) * 1.000002f + 1e-30f;

    if (lane < RPW) cnt[wid][lane] = 0;
    asm volatile("s_waitcnt lgkmcnt(0)" ::: "memory");

    // ===== screen pass: AABB-pruned tiles; append u16 sorted-idx only =====
    for (int t = 0; t < NT; ++t) {
        const float2 mm = tmm[t];
        bool kp[RPW]; bool anyk = false;
#pragma unroll
        for (int r = 0; r < RPW; ++r) {
            const float dx = fmaxf(fmaxf(mm.x - xs[r], xs[r] - mm.y), 0.0f);
            // prune slack: fp32 cancellation bound on ref-d2 vs true-d2
            kp[r] = (dx * dx <= tau[r] * 1.00001f + 5e-5f);
            anyk |= kp[r];
        }
        if (!anyk) continue;        // wave-uniform skip
        const int base = t * 256;
        const float4 q0 = pts[base + lane];
        const float4 q1 = pts[base + 64 + lane];
        const float4 q2 = pts[base + 128 + lane];
        const float4 q3 = pts[base + 192 + lane];
#pragma unroll
        for (int r = 0; r < RPW; ++r) {
            if (!kp[r]) continue;
            const float d0 = (ss[r] + q0.w) - 2.0f * fmaf(zs[r], q0.z, fmaf(ys[r], q0.y, xs[r] * q0.x));
            const float d1 = (ss[r] + q1.w) - 2.0f * fmaf(zs[r], q1.z, fmaf(ys[r], q1.y, xs[r] * q1.x));
            const float d2 = (ss[r] + q2.w) - 2.0f * fmaf(zs[r], q2.z, fmaf(ys[r], q2.y, xs[r] * q2.x));
            const float d3 = (ss[r] + q3.w) - 2.0f * fmaf(zs[r], q3.z, fmaf(ys[r], q3.y, xs[r] * q3.x));
            const bool p0 = d0 <= tau[r], p1 = d1 <= tau[r];
            const bool p2 = d2 <= tau[r], p3 = d3 <= tau[r];
            if (p0 | p1 | p2 | p3) {
                if (p0) { const int o = atomicAdd(&cnt[wid][r], 1);
                          if (o < CAP) buf[wid][r][o] = (u16)(base + lane); }
                if (p1) { const int o = atomicAdd(&cnt[wid][r], 1);
                          if (o < CAP) buf[wid][r][o] = (u16)(base + 64 + lane); }
                if (p2) { const int o = atomicAdd(&cnt[wid][r], 1);
                          if (o < CAP) buf[wid][r][o] = (u16)(base + 128 + lane); }
                if (p3) { const int o = atomicAdd(&cnt[wid][r], 1);
                          if (o < CAP) buf[wid][r][o] = (u16)(base + 192 + lane); }
            }
        }
    }
    asm volatile("s_waitcnt lgkmcnt(0)" ::: "memory");

    // ===== select: recompute d2 (ref arithmetic), exact lex-(dist, orig idx)
    // rank (r14/r20-verified); write neighbors to nbws or ones to out =====
#pragma unroll
    for (int r = 0; r < RPW; ++r) {
        const int C = cnt[wid][r];
        const int row = rowBase + wid * RPW + r;
        if (C <= CAP) {                 // C >= 17 guaranteed (tau subset bound)
            for (int e = lane; e < C; e += 64) {
                const int si = (int)buf[wid][r][e];
                const float4 q = pts[si];
                const float dd = (ss[r] + q.w) - 2.0f * fmaf(zs[r], q.z, fmaf(ys[r], q.y, xs[r] * q.x));
                const float dist = sqrtf(fmaxf(dd, 0.0f));      // IEEE, as ref
                sel[wid][e] = (((u64)__float_as_uint(dist)) << 32) | (unsigned)perm[si];
            }
            asm volatile("s_waitcnt lgkmcnt(0) vmcnt(0)" ::: "memory");
            for (int e = lane; e < C; e += 64) {
                const u64 my = sel[wid][e];
                int rk = 0;
                for (int c = 0; c < C; ++c)
                    rk += (sel[wid][c] < my) ? 1 : 0;   // orig idx unique
                if (rk >= 1 && rk <= KK) {
                    if (nbws) nbws[(size_t)row * KK + rk - 1] = (u16)(my & 0xffffu);
                    else      out[(size_t)row * NN + (int)(my & 0xffffffffu)] = 1.0f;
                }
            }
            asm volatile("s_waitcnt lgkmcnt(0)" ::: "memory");  // before sel reuse
        } else {
            // Pathological overflow: verified full-scan insert, orig-idx keys.
            float ld = INFINITY; int li = 0x7fffffff;
            float td = INFINITY; int ti = 0x7fffffff; float t2 = INFINITY;
            for (int tt = 0; tt < NN / 64; ++tt) {
                const int j = tt * 64 + lane;
                const float4 q = pts[j];
                const int oi = perm[j];
                const float dd = (ss[r] + q.w) - 2.0f * fmaf(zs[r], q.z, fmaf(ys[r], q.y, xs[r] * q.x));
                insert_tile(dd <= t2, dd, oi, ld, li, td, ti, t2, lane);
            }
            if (lane >= 1 && lane <= KK) {
                if (nbws) nbws[(size_t)row * KK + lane - 1] = (u16)li;
                else      out[(size_t)row * NN + li] = 1.0f;
            }
        }
    }
}

// ---------------- mega kernel: 1024 scan blocks + 2048 fill blocks ----------
// Interleaved [scan, fill, fill] by blockIdx%3 so both types co-reside on
// every CU: fill saturates HBM store queues while scan uses VALU + L2 reads.
// Scan blocks write ONLY the nb table (ws); ones stamped by a later kernel.
__global__ __launch_bounds__(256) void mega_kernel(const float4* __restrict__ pts,
                                                   const int* __restrict__ perm,
                                                   const int* __restrict__ cur,
                                                   const float2* __restrict__ tmm_g,
                                                   const float* __restrict__ nodes,
                                                   float* __restrict__ out,
                                                   u16* __restrict__ nbws) {
    const int b = blockIdx.x;
    if (b % 3 != 0) {
        // ---- fill block: identical address pattern to r19/r20 fill_zero ----
        const int fidx = (b / 3) * 2 + (b % 3) - 1;     // [0, 2048)
        const int tid = fidx * 256 + threadIdx.x;
        const int nthreads = FILL_BLOCKS * 256;
        f32x4* ob = (f32x4*)out;
        const f32x4 z4 = {0.f, 0.f, 0.f, 0.f};
#pragma unroll 4
        for (int k = 0; k < (NN * (NN / 4)) / nthreads; ++k)   // 128 iterations
            __builtin_nontemporal_store(z4, ob + (size_t)k * nthreads + tid);
    } else {
        scan_body(b / 3, pts, perm, cur, tmm_g, nodes, nullptr, nbws);
    }
}

// ---------------- ones kernel: stamp 262144 ones after mega completes -------
__global__ __launch_bounds__(256) void ones_kernel(const u16* __restrict__ nbws,
                                                   float* __restrict__ out) {
    const int t = blockIdx.x * 256 + threadIdx.x;     // t < NN*KK
    const int row = t >> 4;
    out[(size_t)row * NN + nbws[t]] = 1.0f;
}

// ---------------- fallback pieces (r20 path, ws too small) ----------------
__global__ __launch_bounds__(256) void fill_zero(f32x4* __restrict__ ob) {
    const int tid = blockIdx.x * 256 + threadIdx.x;
    const int nthreads = FILL_BLOCKS * 256;
    const f32x4 z4 = {0.f, 0.f, 0.f, 0.f};
#pragma unroll 4
    for (int k = 0; k < (NN * (NN / 4)) / nthreads; ++k)
        __builtin_nontemporal_store(z4, ob + (size_t)k * nthreads + tid);
}

__global__ __launch_bounds__(256) void knn_scan_direct(const float4* __restrict__ pts,
                                                       const int* __restrict__ perm,
                                                       const int* __restrict__ cur,
                                                       const float2* __restrict__ tmm_g,
                                                       const float* __restrict__ nodes,
                                                       float* __restrict__ out) {
    scan_body(blockIdx.x, pts, perm, cur, tmm_g, nodes, out, nullptr);
}

extern "C" void kernel_launch(void* const* d_in, const int* in_sizes, int n_in,
                              void* d_out, int out_size, void* d_ws, size_t ws_size,
                              hipStream_t stream) {
    const float* nodes = (const float*)d_in[0];
    float* out = (float*)d_out;
    (void)in_sizes; (void)n_in; (void)out_size;

    char* ws = (char*)d_ws;
    float4* pts  = (float4*)(ws + WS_PTS);
    int*    perm = (int*)   (ws + WS_PERM);
    int*    hist = (int*)   (ws + WS_HIST);
    int*    cur  = (int*)   (ws + WS_CUR);
    float2* tmm  = (float2*)(ws + WS_TMM);
    u16*    nbws = (u16*)   (ws + WS_NB);

    hipLaunchKernelGGL(zero_hist,     dim3(1),        dim3(NB),  0, stream, hist);
    hipLaunchKernelGGL(hist_kernel,   dim3(NN / 256), dim3(256), 0, stream, nodes, hist);
    hipLaunchKernelGGL(scan_kernel,   dim3(1),        dim3(NB),  0, stream, hist, cur);
    hipLaunchKernelGGL(scatter_kernel,dim3(NN / 256), dim3(256), 0, stream, nodes, cur, pts, perm);
    hipLaunchKernelGGL(bounds_kernel, dim3(NT),       dim3(256), 0, stream, pts, tmm);

    if (ws_size >= WS_NEED) {
        hipLaunchKernelGGL(mega_kernel, dim3(SCAN_BLOCKS + FILL_BLOCKS),
                           dim3(256), 0, stream, pts, perm, cur, tmm, nodes, out, nbws);
        hipLaunchKernelGGL(ones_kernel, dim3(NN * KK / 256), dim3(256), 0, stream,
                           nbws, out);
    } else {
        hipLaunchKernelGGL(fill_zero, dim3(FILL_BLOCKS), dim3(256), 0, stream,
                           (f32x4*)out);
        hipLaunchKernelGGL(knn_scan_direct, dim3(SCAN_BLOCKS), dim3(256), 0, stream,
                           pts, perm, cur, tmm, nodes, out);
    }
}